// Round 1
// 3299.627 us; speedup vs baseline: 1.9438x; 1.9438x over previous
//
#include <hip/hip_runtime.h>
#include <math.h>

// Problem constants (fixed by the reference)
#define TDIM  512
#define NB    2
#define SLEN  2048
#define VOCAB 32000
#define NLAYER 3
#define NROW  (NB * SLEN)            // 4096 rows of activations

typedef unsigned short u16;
typedef __attribute__((ext_vector_type(4))) float f32x4;
typedef __attribute__((ext_vector_type(8))) short bf16x8;

static const long SD  = (long)SLEN * TDIM;   // per-batch activation stride
static const long ST  = (long)SLEN * SLEN;   // per-batch score stride
static const long ACT = (long)NB * SLEN * TDIM;
static const long DD  = (long)TDIM * TDIM;

// ---------------- bf16 split helpers (bf16x3 emulation of fp32) ------------
__device__ __forceinline__ u16 f2bf(float x) {          // RNE f32 -> bf16
    unsigned u = __builtin_bit_cast(unsigned, x);
    return (u16)((u + 0x7fffu + ((u >> 16) & 1u)) >> 16);
}
__device__ __forceinline__ float bf2f(u16 h) {
    unsigned u = ((unsigned)h) << 16;
    return __builtin_bit_cast(float, u);
}
__device__ __forceinline__ void split2(float v, u16& h, u16& l) {
    h = f2bf(v);
    l = f2bf(v - bf2f(h));
}

// async global->LDS, 16B per lane; lds base must be wave-uniform
__device__ __forceinline__ void gl16(const u16* g, const u16* l) {
    __builtin_amdgcn_global_load_lds(
        (const __attribute__((address_space(1))) void*)g,
        (__attribute__((address_space(3))) void*)l, 16, 0, 0);
}

// ---------------- block reduction helpers (256 threads = 4 waves) ----------
__device__ __forceinline__ float blockSum256(float v) {
    #pragma unroll
    for (int o = 32; o > 0; o >>= 1) v += __shfl_down(v, o);
    __shared__ float sm[4];
    __syncthreads();
    if ((threadIdx.x & 63) == 0) sm[threadIdx.x >> 6] = v;
    __syncthreads();
    return sm[0] + sm[1] + sm[2] + sm[3];
}

__device__ __forceinline__ float blockMax256(float v) {
    #pragma unroll
    for (int o = 32; o > 0; o >>= 1) v = fmaxf(v, __shfl_down(v, o));
    __shared__ float sm[4];
    __syncthreads();
    if ((threadIdx.x & 63) == 0) sm[threadIdx.x >> 6] = v;
    __syncthreads();
    return fmaxf(fmaxf(sm[0], sm[1]), fmaxf(sm[2], sm[3]));
}

// ---------------- bf16x3 MFMA GEMM -----------------------------------------
// C = alpha * A * B^T (+bias), fp32-accurate via 2-term bf16 splits:
//   a*b ~= ahi*bhi + ahi*blo + alo*bhi   (error ~2^-17 relative)
// A: [M,K] split pair, row stride K. B: [N,K] split pair, row stride K.
// Output: fp32 C (ldc) or split pair Chi/Clo. Batched via blockIdx.z strides.
// Tile BM x BN, BK=32, 4 waves laid 2x2, each computing (BM/2)x(BN/2).
template<int BM, int BN, bool SPLIT_OUT, bool BIAS>
__global__ __launch_bounds__(256)
void gemm_bf3(const u16* __restrict__ Ahi, const u16* __restrict__ Alo,
              const u16* __restrict__ Bhi, const u16* __restrict__ Blo,
              const float* __restrict__ bias,
              float* __restrict__ C, u16* __restrict__ Chi, u16* __restrict__ Clo,
              int K, int ldc, long sA, long sB, long sC, float alpha)
{
    constexpr int MI = BM / 32, NI = BN / 32;   // 16x16 frags per wave (m,n)
    constexpr int IA = BM / 64, IB = BN / 64;   // staging issues per tile
    __shared__ u16 lAh[BM][32], lAl[BM][32], lBh[BN][32], lBl[BN][32];
    Ahi += blockIdx.z * sA;  Alo += blockIdx.z * sA;
    Bhi += blockIdx.z * sB;  Blo += blockIdx.z * sB;
    const int bm = blockIdx.y * BM, bn = blockIdx.x * BN;
    const int tid = threadIdx.x;
    const int w = tid >> 6, l = tid & 63;
    const int wm = (w >> 1) * (BM / 2), wn = (w & 1) * (BN / 2);
    const int srow = l >> 2;            // staging: row within 16-row group
    const int skk  = (l & 3) * 8;       // staging: k element offset (16B units)
    const int frow = l & 15, fkk = (l >> 4) * 8;   // frag coords

    f32x4 acc[MI][NI] = {};

    for (int k0 = 0; k0 < K; k0 += 32) {
        #pragma unroll
        for (int i = 0; i < IA; ++i) {
            const int rr = (w * IA + i) * 16;
            const long go = (long)(bm + rr + srow) * K + k0 + skk;
            gl16(Ahi + go, &lAh[rr][0]);
            gl16(Alo + go, &lAl[rr][0]);
        }
        #pragma unroll
        for (int i = 0; i < IB; ++i) {
            const int rr = (w * IB + i) * 16;
            const long go = (long)(bn + rr + srow) * K + k0 + skk;
            gl16(Bhi + go, &lBh[rr][0]);
            gl16(Blo + go, &lBl[rr][0]);
        }
        __syncthreads();   // compiler emits vmcnt(0) drain before barrier
        bf16x8 ah[MI], al[MI], bh[NI], bl[NI];
        #pragma unroll
        for (int m = 0; m < MI; ++m) {
            ah[m] = *(const bf16x8*)&lAh[wm + m * 16 + frow][fkk];
            al[m] = *(const bf16x8*)&lAl[wm + m * 16 + frow][fkk];
        }
        #pragma unroll
        for (int n = 0; n < NI; ++n) {
            bh[n] = *(const bf16x8*)&lBh[wn + n * 16 + frow][fkk];
            bl[n] = *(const bf16x8*)&lBl[wn + n * 16 + frow][fkk];
        }
        #pragma unroll
        for (int m = 0; m < MI; ++m)
            #pragma unroll
            for (int n = 0; n < NI; ++n) {
                acc[m][n] = __builtin_amdgcn_mfma_f32_16x16x32_bf16(al[m], bh[n], acc[m][n], 0, 0, 0);
                acc[m][n] = __builtin_amdgcn_mfma_f32_16x16x32_bf16(ah[m], bl[n], acc[m][n], 0, 0, 0);
                acc[m][n] = __builtin_amdgcn_mfma_f32_16x16x32_bf16(ah[m], bh[n], acc[m][n], 0, 0, 0);
            }
        __syncthreads();
    }

    // epilogue: C/D layout (verified): col = lane&15, row = (lane>>4)*4 + r
    if constexpr (SPLIT_OUT) { Chi += blockIdx.z * sC; Clo += blockIdx.z * sC; }
    else                     { C   += blockIdx.z * sC; }
    const int r0 = bm + wm + (l >> 4) * 4;
    const int c0 = bn + wn + (l & 15);
    #pragma unroll
    for (int m = 0; m < MI; ++m)
        #pragma unroll
        for (int n = 0; n < NI; ++n) {
            const int col = c0 + n * 16;
            float badd = 0.f;
            if constexpr (BIAS) badd = bias[col];
            #pragma unroll
            for (int r = 0; r < 4; ++r) {
                const long idx = (long)(r0 + m * 16 + r) * ldc + col;
                const float v = acc[m][n][r] * alpha + badd;
                if constexpr (SPLIT_OUT) {
                    u16 h, lo2; split2(v, h, lo2);
                    Chi[idx] = h; Clo[idx] = lo2;
                } else {
                    C[idx] = v;
                }
            }
        }
}

// ---------------- elementwise fp32 -> bf16 hi/lo split ---------------------
__global__ __launch_bounds__(256)
void split_rows(const float* __restrict__ in, u16* __restrict__ oh,
                u16* __restrict__ ol, long n4)
{
    long i = (long)blockIdx.x * 256 + threadIdx.x;
    if (i >= n4) return;
    float4 v = ((const float4*)in)[i];
    ushort4 h, l;
    split2(v.x, h.x, l.x); split2(v.y, h.y, l.y);
    split2(v.z, h.z, l.z); split2(v.w, h.w, l.w);
    ((ushort4*)oh)[i] = h; ((ushort4*)ol)[i] = l;
}

// ---------------- transpose + split: in[K,N] fp32 -> out[N,K] bf16 hi/lo ---
__global__ __launch_bounds__(256)
void transpose_split(const float* __restrict__ in, u16* __restrict__ oh,
                     u16* __restrict__ ol, int K, int N, long sIn, long sOut)
{
    __shared__ float t[32][33];
    in += (long)blockIdx.z * sIn;
    oh += (long)blockIdx.z * sOut;
    ol += (long)blockIdx.z * sOut;
    const int n0 = blockIdx.x * 32, k0 = blockIdx.y * 32;
    const int tx = threadIdx.x & 31, ty = threadIdx.x >> 5;   // ty 0..7
    #pragma unroll
    for (int r = 0; r < 4; ++r) {
        int k = ty * 4 + r;
        t[k][tx] = in[(long)(k0 + k) * N + n0 + tx];
    }
    __syncthreads();
    #pragma unroll
    for (int r = 0; r < 4; ++r) {
        int n = ty * 4 + r;
        float v = t[tx][n];                    // = in[k0+tx][n0+n]
        u16 h, l2; split2(v, h, l2);
        long o = (long)(n0 + n) * K + k0 + tx;
        oh[o] = h; ol[o] = l2;
    }
}

// ---------------- softmax over rows of 2048 -> split bf16 P ----------------
__global__ __launch_bounds__(256)
void softmax2048(const float* __restrict__ s, u16* __restrict__ ph,
                 u16* __restrict__ pl)
{
    long row = blockIdx.x;
    const float* p = s + row * (long)SLEN;
    u16* oh = ph + row * (long)SLEN;
    u16* ol = pl + row * (long)SLEN;
    int t = threadIdx.x;
    float v[8], m = -INFINITY;
    #pragma unroll
    for (int i = 0; i < 8; ++i) { v[i] = p[t + 256 * i]; m = fmaxf(m, v[i]); }
    m = blockMax256(m);
    float sum = 0.f;
    #pragma unroll
    for (int i = 0; i < 8; ++i) { v[i] = expf(v[i] - m); sum += v[i]; }
    sum = blockSum256(sum);
    float inv = 1.0f / sum;
    #pragma unroll
    for (int i = 0; i < 8; ++i) {
        u16 h, l2; split2(v[i] * inv, h, l2);
        oh[t + 256 * i] = h; ol[t + 256 * i] = l2;
    }
}

// ---------------- softmax over rows of 32000 (vocab), in place -------------
__global__ __launch_bounds__(256)
void softmax_vocab(float* __restrict__ out)
{
    long row = blockIdx.x;
    float* p = out + row * (long)VOCAB;
    int t = threadIdx.x;
    float m = -INFINITY, s = 0.f;
    for (int i = t; i < VOCAB; i += 256) {
        float x = p[i];
        if (x > m) { s *= expf(m - x); m = x; }
        s += expf(x - m);
    }
    #pragma unroll
    for (int o = 32; o > 0; o >>= 1) {
        float m2 = __shfl_down(m, o), s2 = __shfl_down(s, o);
        float M = fmaxf(m, m2);
        s = s * expf(m - M) + s2 * expf(m2 - M);
        m = M;
    }
    __shared__ float sm[4], ss[4];
    if ((t & 63) == 0) { sm[t >> 6] = m; ss[t >> 6] = s; }
    __syncthreads();
    float M = fmaxf(fmaxf(sm[0], sm[1]), fmaxf(sm[2], sm[3]));
    float S = ss[0] * expf(sm[0] - M) + ss[1] * expf(sm[1] - M)
            + ss[2] * expf(sm[2] - M) + ss[3] * expf(sm[3] - M);
    float inv = 1.0f / S;
    for (int i = t; i < VOCAB; i += 256) p[i] = expf(p[i] - M) * inv;
}

// ---------------- fused residual + (silu) + layernorm + split --------------
// MODE 0: y = LN(a + r)                (non-affine, attention epilogue)
// MODE 1: y = LN(silu(a) + r) * g + b  (FFN epilogue)
// Writes fp32 y AND its bf16 hi/lo split (feeds the next GEMM's A operand).
template<int MODE>
__global__ __launch_bounds__(256)
void ln_row(const float* __restrict__ a, const float* __restrict__ r,
            const float* __restrict__ g, const float* __restrict__ b,
            float* __restrict__ y, u16* __restrict__ yh, u16* __restrict__ yl)
{
    long row = blockIdx.x;
    const float* pa = a + row * (long)TDIM;
    const float* pr = r + row * (long)TDIM;
    float* py = y + row * (long)TDIM;
    u16* ph = yh + row * (long)TDIM;
    u16* pl = yl + row * (long)TDIM;
    int t = threadIdx.x;
    float v0 = pa[t], v1 = pa[t + 256];
    if (MODE == 1) {
        v0 = v0 / (1.0f + expf(-v0));
        v1 = v1 / (1.0f + expf(-v1));
    }
    v0 += pr[t]; v1 += pr[t + 256];
    float mean = blockSum256(v0 + v1) * (1.0f / TDIM);
    float d0 = v0 - mean, d1 = v1 - mean;
    float var = blockSum256(d0 * d0 + d1 * d1) * (1.0f / TDIM);
    float inv = rsqrtf(var + 1e-5f);
    float y0 = d0 * inv, y1 = d1 * inv;
    if (MODE == 1) {
        y0 = y0 * g[t] + b[t];
        y1 = y1 * g[t + 256] + b[t + 256];
    }
    py[t] = y0; py[t + 256] = y1;
    u16 h0, l0, h1, l1;
    split2(y0, h0, l0); split2(y1, h1, l1);
    ph[t] = h0;       pl[t] = l0;
    ph[t + 256] = h1; pl[t + 256] = l1;
}

// ---------------- host-side orchestration ----------------------------------
extern "C" void kernel_launch(void* const* d_in, const int* in_sizes, int n_in,
                              void* d_out, int out_size, void* d_ws, size_t ws_size,
                              hipStream_t stream)
{
    (void)in_sizes; (void)n_in; (void)out_size; (void)ws_size;
    const float* X   = (const float*)d_in[0];
    const float* Y   = (const float*)d_in[1];
    const float* EWQ = (const float*)d_in[2];
    const float* EWK = (const float*)d_in[3];
    const float* EWV = (const float*)d_in[4];
    const float* EFW = (const float*)d_in[5];
    const float* EFB = (const float*)d_in[6];
    const float* EG  = (const float*)d_in[7];
    const float* EB  = (const float*)d_in[8];
    const float* DSQ = (const float*)d_in[9];
    const float* DSK = (const float*)d_in[10];
    const float* DSV = (const float*)d_in[11];
    const float* DCQ = (const float*)d_in[12];
    const float* DCK = (const float*)d_in[13];
    const float* DCV = (const float*)d_in[14];
    const float* DFW = (const float*)d_in[15];
    const float* DFB = (const float*)d_in[16];
    const float* DG  = (const float*)d_in[17];
    const float* DB  = (const float*)d_in[18];
    const float* FCW = (const float*)d_in[19];
    float* OUT = (float*)d_out;

    // workspace layout (~276 MB)
    char* p = (char*)d_ws;
    auto AF = [&](long n) { float* r = (float*)p; p += n * 4; return r; };
    auto AH = [&](long n) { u16*   r = (u16*)p;   p += n * 2; return r; };
    float* bx  = AF(ACT);            // encoder state / encoder output (fp32)
    float* bt  = AF(ACT);            // attn/ffn pre-LN temp
    float* bv  = AF(ACT);            // V projection (fp32, pre-transpose)
    float* bh1 = AF(ACT);            // decoder self-attn out
    float* bh2 = AF(ACT);            // decoder cross-attn out
    float* bo  = AF(ACT);            // decoder running state
    float* bs  = AF((long)NB * ST);  // fp32 attention scores
    u16 *xs_h = AH(ACT), *xs_l = AH(ACT);       // split of bx
    u16 *h1_h = AH(ACT), *h1_l = AH(ACT);       // split of bh1
    u16 *h2_h = AH(ACT), *h2_l = AH(ACT);       // split of bh2
    u16 *os_h = AH(ACT), *os_l = AH(ACT);       // split of bo
    u16 *qs_h = AH(ACT), *qs_l = AH(ACT);       // split q
    u16 *ks_h = AH(ACT), *ks_l = AH(ACT);       // split k
    u16 *vt_h = AH(ACT), *vt_l = AH(ACT);       // split V^T [NB,512,2048]
    u16 *ps_h = AH((long)NB * ST), *ps_l = AH((long)NB * ST); // split P
    u16 *W_h[11], *W_l[11];                     // transposed split weights
    for (int i = 0; i < 11; ++i) { W_h[i] = AH(3 * DD); W_l[i] = AH(3 * DD); }
    u16 *fc_h = AH((long)TDIM * VOCAB), *fc_l = AH((long)TDIM * VOCAB);

    dim3 blk(256);

    // ---- one-time operand prep (per launch) ----
    hipMemcpyAsync(bx, X, ACT * 4, hipMemcpyDeviceToDevice, stream);
    hipMemcpyAsync(bo, Y, ACT * 4, hipMemcpyDeviceToDevice, stream);
    split_rows<<<dim3(ACT / 1024), blk, 0, stream>>>(X, xs_h, xs_l, ACT / 4);
    split_rows<<<dim3(ACT / 1024), blk, 0, stream>>>(Y, os_h, os_l, ACT / 4);
    const float* Wsrc[11] = {EWQ, EWK, EWV, EFW, DSQ, DSK, DSV, DCQ, DCK, DCV, DFW};
    for (int i = 0; i < 11; ++i)
        transpose_split<<<dim3(16, 16, 3), blk, 0, stream>>>(
            Wsrc[i], W_h[i], W_l[i], TDIM, TDIM, DD, DD);
    transpose_split<<<dim3(VOCAB / 32, 16, 1), blk, 0, stream>>>(
        FCW, fc_h, fc_l, TDIM, VOCAB, 0, 0);

    // full single-head attention: dst = LN(softmax(xq Wq (ctx Wk)^T / 8) ctx Wv + xq)
    auto attn = [&](const float* xqf, const u16* xqh, const u16* xql,
                    const u16* cxh, const u16* cxl,
                    const u16* wqh, const u16* wql, const u16* wkh, const u16* wkl,
                    const u16* wvh, const u16* wvl,
                    float* dst, u16* dsth, u16* dstl) {
        // q,k projections: split output straight into qs/ks
        gemm_bf3<64, 128, true, false><<<dim3(TDIM / 128, NROW / 64, 1), blk, 0, stream>>>(
            xqh, xql, wqh, wql, nullptr, nullptr, qs_h, qs_l, TDIM, TDIM, 0, 0, 0, 1.0f);
        gemm_bf3<64, 128, true, false><<<dim3(TDIM / 128, NROW / 64, 1), blk, 0, stream>>>(
            cxh, cxl, wkh, wkl, nullptr, nullptr, ks_h, ks_l, TDIM, TDIM, 0, 0, 0, 1.0f);
        // v projection: fp32 out, then transpose+split to [512,2048] per batch
        gemm_bf3<64, 128, false, false><<<dim3(TDIM / 128, NROW / 64, 1), blk, 0, stream>>>(
            cxh, cxl, wvh, wvl, nullptr, bv, nullptr, nullptr, TDIM, TDIM, 0, 0, 0, 1.0f);
        transpose_split<<<dim3(TDIM / 32, SLEN / 32, NB), blk, 0, stream>>>(
            bv, vt_h, vt_l, SLEN, TDIM, SD, SD);
        // scores = q k^T / 8 (fp32), batched
        gemm_bf3<128, 128, false, false><<<dim3(SLEN / 128, SLEN / 128, NB), blk, 0, stream>>>(
            qs_h, qs_l, ks_h, ks_l, nullptr, bs, nullptr, nullptr, TDIM, SLEN, SD, SD, ST, 0.125f);
        softmax2048<<<dim3(NROW), blk, 0, stream>>>(bs, ps_h, ps_l);
        // pv = P @ V = P @ (V^T)^T, batched
        gemm_bf3<64, 128, false, false><<<dim3(TDIM / 128, SLEN / 64, NB), blk, 0, stream>>>(
            ps_h, ps_l, vt_h, vt_l, nullptr, bt, nullptr, nullptr, SLEN, TDIM, ST, SD, SD, 1.0f);
        ln_row<0><<<dim3(NROW), blk, 0, stream>>>(bt, xqf, nullptr, nullptr, dst, dsth, dstl);
    };
    auto ffn = [&](const float* xf, const u16* xh, const u16* xl,
                   const u16* fwh, const u16* fwl, const float* fb,
                   const float* g_, const float* b_,
                   float* dst, u16* dh, u16* dl) {
        gemm_bf3<64, 128, false, true><<<dim3(TDIM / 128, NROW / 64, 1), blk, 0, stream>>>(
            xh, xl, fwh, fwl, fb, bt, nullptr, nullptr, TDIM, TDIM, 0, 0, 0, 1.0f);
        ln_row<1><<<dim3(NROW), blk, 0, stream>>>(bt, xf, g_, b_, dst, dh, dl);
    };

    // ---- encoder ----
    for (int i = 0; i < NLAYER; ++i) {
        attn(bx, xs_h, xs_l, xs_h, xs_l,
             W_h[0] + i * DD, W_l[0] + i * DD, W_h[1] + i * DD, W_l[1] + i * DD,
             W_h[2] + i * DD, W_l[2] + i * DD, bx, xs_h, xs_l);
        ffn(bx, xs_h, xs_l, W_h[3] + i * DD, W_l[3] + i * DD,
            EFB + i * TDIM, EG + i * TDIM, EB + i * TDIM, bx, xs_h, xs_l);
    }

    // ---- decoder ----
    for (int i = 0; i < NLAYER; ++i) {
        attn(bx, xs_h, xs_l, xs_h, xs_l,
             W_h[4] + i * DD, W_l[4] + i * DD, W_h[5] + i * DD, W_l[5] + i * DD,
             W_h[6] + i * DD, W_l[6] + i * DD, bh1, h1_h, h1_l);
        attn(bh1, h1_h, h1_l, os_h, os_l,
             W_h[7] + i * DD, W_l[7] + i * DD, W_h[8] + i * DD, W_l[8] + i * DD,
             W_h[9] + i * DD, W_l[9] + i * DD, bh2, h2_h, h2_l);
        ffn(bh2, h2_h, h2_l, W_h[10] + i * DD, W_l[10] + i * DD,
            DFB + i * TDIM, DG + i * TDIM, DB + i * TDIM, bo, os_h, os_l);
    }

    // ---- final projection to vocab (fp32 logits into d_out) + softmax ----
    gemm_bf3<128, 128, false, false><<<dim3(VOCAB / 128, NROW / 128, 1), blk, 0, stream>>>(
        os_h, os_l, fc_h, fc_l, nullptr, OUT, nullptr, nullptr, TDIM, VOCAB, 0, 0, 0, 1.0f);
    softmax_vocab<<<dim3(NROW), blk, 0, stream>>>(OUT);
}

// Round 2
// 3057.201 us; speedup vs baseline: 2.0980x; 1.0793x over previous
//
#include <hip/hip_runtime.h>
#include <math.h>

// Problem constants (fixed by the reference)
#define TDIM  512
#define NB    2
#define SLEN  2048
#define VOCAB 32000
#define NLAYER 3
#define NROW  (NB * SLEN)            // 4096 rows of activations

typedef unsigned short u16;
typedef __attribute__((ext_vector_type(4))) float f32x4;
typedef __attribute__((ext_vector_type(8))) short bf16x8;

static const long SD  = (long)SLEN * TDIM;   // per-batch activation stride
static const long ST  = (long)SLEN * SLEN;   // per-batch score stride
static const long ACT = (long)NB * SLEN * TDIM;
static const long DD  = (long)TDIM * TDIM;
static const long S2  = (long)SLEN * 1024;   // per-batch stride of fused Q|K buf

// ---------------- bf16 split helpers (bf16x3 emulation of fp32) ------------
__device__ __forceinline__ u16 f2bf(float x) {          // RNE f32 -> bf16
    unsigned u = __builtin_bit_cast(unsigned, x);
    return (u16)((u + 0x7fffu + ((u >> 16) & 1u)) >> 16);
}
__device__ __forceinline__ float bf2f(u16 h) {
    unsigned u = ((unsigned)h) << 16;
    return __builtin_bit_cast(float, u);
}
__device__ __forceinline__ void split2(float v, u16& h, u16& l) {
    h = f2bf(v);
    l = f2bf(v - bf2f(h));
}

// async global->LDS, 16B per lane; lds base must be wave-uniform
__device__ __forceinline__ void gl16(const u16* g, const u16* l) {
    __builtin_amdgcn_global_load_lds(
        (const __attribute__((address_space(1))) void*)g,
        (__attribute__((address_space(3))) void*)l, 16, 0, 0);
}

// ---------------- block reduction helpers (256 threads = 4 waves) ----------
__device__ __forceinline__ float blockSum256(float v) {
    #pragma unroll
    for (int o = 32; o > 0; o >>= 1) v += __shfl_down(v, o);
    __shared__ float sm[4];
    __syncthreads();
    if ((threadIdx.x & 63) == 0) sm[threadIdx.x >> 6] = v;
    __syncthreads();
    return sm[0] + sm[1] + sm[2] + sm[3];
}

__device__ __forceinline__ float blockMax256(float v) {
    #pragma unroll
    for (int o = 32; o > 0; o >>= 1) v = fmaxf(v, __shfl_down(v, o));
    __shared__ float sm[4];
    __syncthreads();
    if ((threadIdx.x & 63) == 0) sm[threadIdx.x >> 6] = v;
    __syncthreads();
    return fmaxf(fmaxf(sm[0], sm[1]), fmaxf(sm[2], sm[3]));
}

// ---------------- bf16x3 MFMA GEMM -----------------------------------------
// C = alpha * A * B^T (+bias), fp32-accurate via 2-term bf16 splits:
//   a*b ~= ahi*bhi + ahi*blo + alo*bhi   (error ~2^-17 relative)
// A: [M,K]-ish rows with leading dim lda (split pair). B: [N,K]-ish, ldb.
// Output: fp32 C (ldc) or split pair Chi/Clo (ldc). Batched via blockIdx.z.
// Tile BM x BN, BK=64, 4 waves laid 2x2, each computing (BM/2)x(BN/2).
// LDS layout XOR-swizzled (T2) via pre-swizzled global source (gl16 dest is
// linear): elem-col swizzle = ((col/8) ^ (row&7))*8 within the 64-elem row.
template<int BM, int BN, bool SPLIT_OUT, bool BIAS, bool SWZ>
__global__ __launch_bounds__(256)
void gemm_bf3(const u16* __restrict__ Ahi, const u16* __restrict__ Alo, int lda,
              const u16* __restrict__ Bhi, const u16* __restrict__ Blo, int ldb,
              const float* __restrict__ bias,
              float* __restrict__ C, u16* __restrict__ Chi, u16* __restrict__ Clo,
              int ldc, int K, long sA, long sB, long sC, float alpha)
{
    constexpr int MI = BM / 32, NI = BN / 32;    // 16x16 frags per wave
    constexpr int IA = BM / 32, IB = BN / 32;    // gl16 issues per wave per buf
    __shared__ u16 lAh[BM][64], lAl[BM][64], lBh[BN][64], lBl[BN][64];
    Ahi += blockIdx.z * sA;  Alo += blockIdx.z * sA;
    Bhi += blockIdx.z * sB;  Blo += blockIdx.z * sB;
    int bxi = blockIdx.x, byi = blockIdx.y;
    if (SWZ) {   // XCD-aware remap (requires gridDim.x*gridDim.y % 8 == 0)
        const int nwg = gridDim.x * gridDim.y;
        int bid = byi * gridDim.x + bxi;
        bid = (bid & 7) * (nwg >> 3) + (bid >> 3);
        bxi = bid % gridDim.x; byi = bid / gridDim.x;
    }
    const int bm = byi * BM, bn = bxi * BN;
    const int tid = threadIdx.x;
    const int w = tid >> 6, l = tid & 63;
    const int wm = (w >> 1) * (BM / 2), wn = (w & 1) * (BN / 2);
    const int srow = l >> 3;                      // staging row within 8-group
    const int scol = ((l & 7) ^ srow) * 8;        // pre-swizzled k elem offset
    const int frow = l & 15, fk = (l >> 4) * 8;   // frag coords
    const int rsw  = (frow & 7) * 8;              // read-side swizzle

    f32x4 acc[MI][NI] = {};

    for (int k0 = 0; k0 < K; k0 += 64) {
        #pragma unroll
        for (int i = 0; i < IA; ++i) {
            const int rr = (w * IA + i) * 8;
            const long go = (long)(bm + rr + srow) * lda + k0 + scol;
            gl16(Ahi + go, &lAh[rr][0]);
            gl16(Alo + go, &lAl[rr][0]);
        }
        #pragma unroll
        for (int i = 0; i < IB; ++i) {
            const int rr = (w * IB + i) * 8;
            const long go = (long)(bn + rr + srow) * ldb + k0 + scol;
            gl16(Bhi + go, &lBh[rr][0]);
            gl16(Blo + go, &lBl[rr][0]);
        }
        __syncthreads();   // compiler emits vmcnt(0) drain before barrier
        #pragma unroll
        for (int c = 0; c < 2; ++c) {
            bf16x8 ah[MI], av[MI], bh[NI], bv[NI];
            #pragma unroll
            for (int m = 0; m < MI; ++m) {
                const int row = wm + m * 16 + frow;
                const int col = (c * 32 + fk) ^ rsw;
                ah[m] = *(const bf16x8*)&lAh[row][col];
                av[m] = *(const bf16x8*)&lAl[row][col];
            }
            #pragma unroll
            for (int n = 0; n < NI; ++n) {
                const int row = wn + n * 16 + frow;
                const int col = (c * 32 + fk) ^ rsw;
                bh[n] = *(const bf16x8*)&lBh[row][col];
                bv[n] = *(const bf16x8*)&lBl[row][col];
            }
            #pragma unroll
            for (int m = 0; m < MI; ++m)
                #pragma unroll
                for (int n = 0; n < NI; ++n) {
                    acc[m][n] = __builtin_amdgcn_mfma_f32_16x16x32_bf16(av[m], bh[n], acc[m][n], 0, 0, 0);
                    acc[m][n] = __builtin_amdgcn_mfma_f32_16x16x32_bf16(ah[m], bv[n], acc[m][n], 0, 0, 0);
                    acc[m][n] = __builtin_amdgcn_mfma_f32_16x16x32_bf16(ah[m], bh[n], acc[m][n], 0, 0, 0);
                }
        }
        __syncthreads();
    }

    // epilogue: C/D layout (verified): col = lane&15, row = (lane>>4)*4 + r
    if constexpr (SPLIT_OUT) { Chi += blockIdx.z * sC; Clo += blockIdx.z * sC; }
    else                     { C   += blockIdx.z * sC; }
    const int r0 = bm + wm + (l >> 4) * 4;
    const int c0 = bn + wn + (l & 15);
    #pragma unroll
    for (int m = 0; m < MI; ++m)
        #pragma unroll
        for (int n = 0; n < NI; ++n) {
            const int col = c0 + n * 16;
            float badd = 0.f;
            if constexpr (BIAS) badd = bias[col];
            #pragma unroll
            for (int r = 0; r < 4; ++r) {
                const long idx = (long)(r0 + m * 16 + r) * ldc + col;
                const float v = acc[m][n][r] * alpha + badd;
                if constexpr (SPLIT_OUT) {
                    u16 h, lo2; split2(v, h, lo2);
                    Chi[idx] = h; Clo[idx] = lo2;
                } else {
                    C[idx] = v;
                }
            }
        }
}

// ---------------- elementwise fp32 -> bf16 hi/lo split ---------------------
__global__ __launch_bounds__(256)
void split_rows(const float* __restrict__ in, u16* __restrict__ oh,
                u16* __restrict__ ol, long n4)
{
    long i = (long)blockIdx.x * 256 + threadIdx.x;
    if (i >= n4) return;
    float4 v = ((const float4*)in)[i];
    ushort4 h, l;
    split2(v.x, h.x, l.x); split2(v.y, h.y, l.y);
    split2(v.z, h.z, l.z); split2(v.w, h.w, l.w);
    ((ushort4*)oh)[i] = h; ((ushort4*)ol)[i] = l;
}

// ---------------- transpose + split: in[K,N] fp32 -> out[N,K] bf16 hi/lo ---
__global__ __launch_bounds__(256)
void transpose_split(const float* __restrict__ in, u16* __restrict__ oh,
                     u16* __restrict__ ol, int K, int N, long sIn, long sOut)
{
    __shared__ float t[32][33];
    in += (long)blockIdx.z * sIn;
    oh += (long)blockIdx.z * sOut;
    ol += (long)blockIdx.z * sOut;
    const int n0 = blockIdx.x * 32, k0 = blockIdx.y * 32;
    const int tx = threadIdx.x & 31, ty = threadIdx.x >> 5;   // ty 0..7
    #pragma unroll
    for (int r = 0; r < 4; ++r) {
        int k = ty * 4 + r;
        t[k][tx] = in[(long)(k0 + k) * N + n0 + tx];
    }
    __syncthreads();
    #pragma unroll
    for (int r = 0; r < 4; ++r) {
        int n = ty * 4 + r;
        float v = t[tx][n];                    // = in[k0+tx][n0+n]
        u16 h, l2; split2(v, h, l2);
        long o = (long)(n0 + n) * K + k0 + tx;
        oh[o] = h; ol[o] = l2;
    }
}

// ---------------- softmax over rows of 2048 -> split bf16 P ----------------
__global__ __launch_bounds__(256)
void softmax2048(const float* __restrict__ s, u16* __restrict__ ph,
                 u16* __restrict__ pl)
{
    long row = blockIdx.x;
    const float* p = s + row * (long)SLEN;
    u16* oh = ph + row * (long)SLEN;
    u16* ol = pl + row * (long)SLEN;
    int t = threadIdx.x;
    float v[8], m = -INFINITY;
    #pragma unroll
    for (int i = 0; i < 8; ++i) { v[i] = p[t + 256 * i]; m = fmaxf(m, v[i]); }
    m = blockMax256(m);
    float sum = 0.f;
    #pragma unroll
    for (int i = 0; i < 8; ++i) { v[i] = expf(v[i] - m); sum += v[i]; }
    sum = blockSum256(sum);
    float inv = 1.0f / sum;
    #pragma unroll
    for (int i = 0; i < 8; ++i) {
        u16 h, l2; split2(v[i] * inv, h, l2);
        oh[t + 256 * i] = h; ol[t + 256 * i] = l2;
    }
}

// ---------------- softmax over rows of 32000 (vocab), in place -------------
__global__ __launch_bounds__(256)
void softmax_vocab(float* __restrict__ out)
{
    long row = blockIdx.x;
    float* p = out + row * (long)VOCAB;
    int t = threadIdx.x;
    float m = -INFINITY, s = 0.f;
    for (int i = t; i < VOCAB; i += 256) {
        float x = p[i];
        if (x > m) { s *= expf(m - x); m = x; }
        s += expf(x - m);
    }
    #pragma unroll
    for (int o = 32; o > 0; o >>= 1) {
        float m2 = __shfl_down(m, o), s2 = __shfl_down(s, o);
        float M = fmaxf(m, m2);
        s = s * expf(m - M) + s2 * expf(m2 - M);
        m = M;
    }
    __shared__ float sm[4], ss[4];
    if ((t & 63) == 0) { sm[t >> 6] = m; ss[t >> 6] = s; }
    __syncthreads();
    float M = fmaxf(fmaxf(sm[0], sm[1]), fmaxf(sm[2], sm[3]));
    float S = ss[0] * expf(sm[0] - M) + ss[1] * expf(sm[1] - M)
            + ss[2] * expf(sm[2] - M) + ss[3] * expf(sm[3] - M);
    float inv = 1.0f / S;
    for (int i = t; i < VOCAB; i += 256) p[i] = expf(p[i] - M) * inv;
}

// ---------------- fused residual + (silu) + layernorm + split --------------
// MODE 0: y = LN(a + r)                (non-affine, attention epilogue)
// MODE 1: y = LN(silu(a) + r) * g + b  (FFN epilogue)
// Writes fp32 y AND its bf16 hi/lo split (feeds the next GEMM's A operand).
template<int MODE>
__global__ __launch_bounds__(256)
void ln_row(const float* __restrict__ a, const float* __restrict__ r,
            const float* __restrict__ g, const float* __restrict__ b,
            float* __restrict__ y, u16* __restrict__ yh, u16* __restrict__ yl)
{
    long row = blockIdx.x;
    const float* pa = a + row * (long)TDIM;
    const float* pr = r + row * (long)TDIM;
    float* py = y + row * (long)TDIM;
    u16* ph = yh + row * (long)TDIM;
    u16* pl = yl + row * (long)TDIM;
    int t = threadIdx.x;
    float v0 = pa[t], v1 = pa[t + 256];
    if (MODE == 1) {
        v0 = v0 / (1.0f + expf(-v0));
        v1 = v1 / (1.0f + expf(-v1));
    }
    v0 += pr[t]; v1 += pr[t + 256];
    float mean = blockSum256(v0 + v1) * (1.0f / TDIM);
    float d0 = v0 - mean, d1 = v1 - mean;
    float var = blockSum256(d0 * d0 + d1 * d1) * (1.0f / TDIM);
    float inv = rsqrtf(var + 1e-5f);
    float y0 = d0 * inv, y1 = d1 * inv;
    if (MODE == 1) {
        y0 = y0 * g[t] + b[t];
        y1 = y1 * g[t + 256] + b[t + 256];
    }
    py[t] = y0; py[t + 256] = y1;
    u16 h0, l0, h1, l1;
    split2(y0, h0, l0); split2(y1, h1, l1);
    ph[t] = h0;       pl[t] = l0;
    ph[t + 256] = h1; pl[t + 256] = l1;
}

// ---------------- host-side orchestration ----------------------------------
extern "C" void kernel_launch(void* const* d_in, const int* in_sizes, int n_in,
                              void* d_out, int out_size, void* d_ws, size_t ws_size,
                              hipStream_t stream)
{
    (void)in_sizes; (void)n_in; (void)out_size; (void)ws_size;
    const float* X   = (const float*)d_in[0];
    const float* Y   = (const float*)d_in[1];
    const float* EWQ = (const float*)d_in[2];
    const float* EWK = (const float*)d_in[3];
    const float* EWV = (const float*)d_in[4];
    const float* EFW = (const float*)d_in[5];
    const float* EFB = (const float*)d_in[6];
    const float* EG  = (const float*)d_in[7];
    const float* EB  = (const float*)d_in[8];
    const float* DSQ = (const float*)d_in[9];
    const float* DSK = (const float*)d_in[10];
    const float* DSV = (const float*)d_in[11];
    const float* DCQ = (const float*)d_in[12];
    const float* DCK = (const float*)d_in[13];
    const float* DCV = (const float*)d_in[14];
    const float* DFW = (const float*)d_in[15];
    const float* DFB = (const float*)d_in[16];
    const float* DG  = (const float*)d_in[17];
    const float* DB  = (const float*)d_in[18];
    const float* FCW = (const float*)d_in[19];
    float* OUT = (float*)d_out;

    // workspace layout (~300 MB)
    char* p = (char*)d_ws;
    auto AF = [&](long n) { float* r = (float*)p; p += n * 4; return r; };
    auto AH = [&](long n) { u16*   r = (u16*)p;   p += n * 2; return r; };
    float* bx  = AF(ACT);            // encoder state / encoder output (fp32)
    float* bt  = AF(ACT);            // attn/ffn pre-LN temp
    float* bh1 = AF(ACT);            // decoder self-attn out
    float* bh2 = AF(ACT);            // decoder cross-attn out
    float* bo  = AF(ACT);            // decoder running state (never read; LN dst)
    float* bs  = AF((long)NB * ST);  // fp32 attention scores
    u16 *xs_h = AH(ACT), *xs_l = AH(ACT);       // split of bx
    u16 *h1_h = AH(ACT), *h1_l = AH(ACT);       // split of bh1
    u16 *h2_h = AH(ACT), *h2_l = AH(ACT);       // split of bh2
    u16 *os_h = AH(ACT), *os_l = AH(ACT);       // split of decoder state
    u16 *qk_h = AH((long)NROW * 1024), *qk_l = AH((long)NROW * 1024); // fused Q|K
    u16 *vt_h = AH(ACT), *vt_l = AH(ACT);       // split V^T [NB,512,2048]
    u16 *ps_h = AH((long)NB * ST), *ps_l = AH((long)NB * ST); // split P
    // transposed split weights: per layer [WqT | WkT] (2*DD) and WvT (DD)
    u16 *eqk_h = AH(3 * 2 * DD), *eqk_l = AH(3 * 2 * DD);
    u16 *ev_h  = AH(3 * DD),     *ev_l  = AH(3 * DD);
    u16 *dsqk_h= AH(3 * 2 * DD), *dsqk_l= AH(3 * 2 * DD);
    u16 *dsv_h = AH(3 * DD),     *dsv_l = AH(3 * DD);
    u16 *dcqk_h= AH(3 * 2 * DD), *dcqk_l= AH(3 * 2 * DD);
    u16 *dcv_h = AH(3 * DD),     *dcv_l = AH(3 * DD);
    u16 *efw_h = AH(3 * DD),     *efw_l = AH(3 * DD);
    u16 *dfw_h = AH(3 * DD),     *dfw_l = AH(3 * DD);
    u16 *fc_h  = AH((long)TDIM * VOCAB), *fc_l = AH((long)TDIM * VOCAB);

    dim3 blk(256);

    // ---- one-time operand prep (per launch) ----
    split_rows<<<dim3(ACT / 1024), blk, 0, stream>>>(X, xs_h, xs_l, ACT / 4);
    split_rows<<<dim3(ACT / 1024), blk, 0, stream>>>(Y, os_h, os_l, ACT / 4);
    transpose_split<<<dim3(16, 16, 3), blk, 0, stream>>>(EWQ, eqk_h,      eqk_l,      TDIM, TDIM, DD, 2 * DD);
    transpose_split<<<dim3(16, 16, 3), blk, 0, stream>>>(EWK, eqk_h + DD, eqk_l + DD, TDIM, TDIM, DD, 2 * DD);
    transpose_split<<<dim3(16, 16, 3), blk, 0, stream>>>(EWV, ev_h,  ev_l,  TDIM, TDIM, DD, DD);
    transpose_split<<<dim3(16, 16, 3), blk, 0, stream>>>(DSQ, dsqk_h,      dsqk_l,      TDIM, TDIM, DD, 2 * DD);
    transpose_split<<<dim3(16, 16, 3), blk, 0, stream>>>(DSK, dsqk_h + DD, dsqk_l + DD, TDIM, TDIM, DD, 2 * DD);
    transpose_split<<<dim3(16, 16, 3), blk, 0, stream>>>(DSV, dsv_h, dsv_l, TDIM, TDIM, DD, DD);
    transpose_split<<<dim3(16, 16, 3), blk, 0, stream>>>(DCQ, dcqk_h,      dcqk_l,      TDIM, TDIM, DD, 2 * DD);
    transpose_split<<<dim3(16, 16, 3), blk, 0, stream>>>(DCK, dcqk_h + DD, dcqk_l + DD, TDIM, TDIM, DD, 2 * DD);
    transpose_split<<<dim3(16, 16, 3), blk, 0, stream>>>(DCV, dcv_h, dcv_l, TDIM, TDIM, DD, DD);
    transpose_split<<<dim3(16, 16, 3), blk, 0, stream>>>(EFW, efw_h, efw_l, TDIM, TDIM, DD, DD);
    transpose_split<<<dim3(16, 16, 3), blk, 0, stream>>>(DFW, dfw_h, dfw_l, TDIM, TDIM, DD, DD);
    transpose_split<<<dim3(VOCAB / 32, 16, 1), blk, 0, stream>>>(FCW, fc_h, fc_l, TDIM, VOCAB, 0, 0);

    // shared attention tail: V^T proj, scores, softmax, PV, LN.
    // Assumes qk buffer holds [Q | K] (ld 1024) for this attention.
    auto attn_core = [&](const float* resf, const u16* ctxh, const u16* ctxl,
                         const u16* vwh, const u16* vwl,
                         float* dst, u16* dsth, u16* dstl) {
        // V^T[d,t] = sum_k WvT[d,k] * ctx[t,k]  -> split out, [NB,512,2048]
        gemm_bf3<64, 128, true, false, false><<<dim3(16, 8, NB), blk, 0, stream>>>(
            vwh, vwl, TDIM, ctxh, ctxl, TDIM, nullptr,
            nullptr, vt_h, vt_l, SLEN, TDIM, 0, SD, SD, 1.0f);
        // scores = Q K^T / 8 (fp32)
        gemm_bf3<64, 128, false, false, false><<<dim3(16, 32, NB), blk, 0, stream>>>(
            qk_h, qk_l, 1024, qk_h + 512, qk_l + 512, 1024, nullptr,
            bs, nullptr, nullptr, SLEN, TDIM, S2, S2, ST, 0.125f);
        softmax2048<<<dim3(NROW), blk, 0, stream>>>(bs, ps_h, ps_l);
        // PV = P @ (V^T)^T
        gemm_bf3<64, 128, false, false, false><<<dim3(4, 32, NB), blk, 0, stream>>>(
            ps_h, ps_l, SLEN, vt_h, vt_l, SLEN, nullptr,
            bt, nullptr, nullptr, TDIM, SLEN, ST, SD, SD, 1.0f);
        ln_row<0><<<dim3(NROW), blk, 0, stream>>>(bt, resf, nullptr, nullptr, dst, dsth, dstl);
    };
    // self-attention: fused Q|K projection (N=1024) from the same input
    auto attn_self = [&](const float* xf, const u16* xh, const u16* xl,
                         const u16* qkwh, const u16* qkwl,
                         const u16* vwh, const u16* vwl,
                         float* dst, u16* dsth, u16* dstl) {
        gemm_bf3<64, 128, true, false, false><<<dim3(8, 64, 1), blk, 0, stream>>>(
            xh, xl, TDIM, qkwh, qkwl, TDIM, nullptr,
            nullptr, qk_h, qk_l, 1024, TDIM, 0, 0, 0, 1.0f);
        attn_core(xf, xh, xl, vwh, vwl, dst, dsth, dstl);
    };
    // cross-attention: Q from (qf,qh,ql), K/V from ctx (ch,cl)
    auto attn_cross = [&](const float* qf, const u16* qh, const u16* ql,
                          const u16* ch, const u16* cl,
                          const u16* qkwh, const u16* qkwl,
                          const u16* vwh, const u16* vwl,
                          float* dst, u16* dsth, u16* dstl) {
        gemm_bf3<64, 128, true, false, false><<<dim3(4, 64, 1), blk, 0, stream>>>(
            qh, ql, TDIM, qkwh, qkwl, TDIM, nullptr,
            nullptr, qk_h, qk_l, 1024, TDIM, 0, 0, 0, 1.0f);
        gemm_bf3<64, 128, true, false, false><<<dim3(4, 64, 1), blk, 0, stream>>>(
            ch, cl, TDIM, qkwh + DD, qkwl + DD, TDIM, nullptr,
            nullptr, qk_h + 512, qk_l + 512, 1024, TDIM, 0, 0, 0, 1.0f);
        attn_core(qf, ch, cl, vwh, vwl, dst, dsth, dstl);
    };
    auto ffn = [&](const float* xf, const u16* xh, const u16* xl,
                   const u16* fwh, const u16* fwl, const float* fb,
                   const float* g_, const float* b_,
                   float* dst, u16* dh, u16* dl) {
        gemm_bf3<64, 128, false, true, false><<<dim3(4, 64, 1), blk, 0, stream>>>(
            xh, xl, TDIM, fwh, fwl, TDIM, fb,
            bt, nullptr, nullptr, TDIM, TDIM, 0, 0, 0, 1.0f);
        ln_row<1><<<dim3(NROW), blk, 0, stream>>>(bt, xf, g_, b_, dst, dh, dl);
    };

    // ---- encoder ----
    for (int i = 0; i < NLAYER; ++i) {
        attn_self(i == 0 ? X : bx, xs_h, xs_l,
                  eqk_h + i * 2 * DD, eqk_l + i * 2 * DD,
                  ev_h + i * DD, ev_l + i * DD, bx, xs_h, xs_l);
        ffn(bx, xs_h, xs_l, efw_h + i * DD, efw_l + i * DD,
            EFB + i * TDIM, EG + i * TDIM, EB + i * TDIM, bx, xs_h, xs_l);
    }

    // ---- decoder ----
    for (int i = 0; i < NLAYER; ++i) {
        attn_self(bx, xs_h, xs_l,
                  dsqk_h + i * 2 * DD, dsqk_l + i * 2 * DD,
                  dsv_h + i * DD, dsv_l + i * DD, bh1, h1_h, h1_l);
        attn_cross(bh1, h1_h, h1_l, os_h, os_l,
                   dcqk_h + i * 2 * DD, dcqk_l + i * 2 * DD,
                   dcv_h + i * DD, dcv_l + i * DD, bh2, h2_h, h2_l);
        ffn(bh2, h2_h, h2_l, dfw_h + i * DD, dfw_l + i * DD,
            DFB + i * TDIM, DG + i * TDIM, DB + i * TDIM, bo, os_h, os_l);
    }

    // ---- final projection to vocab (fp32 logits into d_out) + softmax ----
    gemm_bf3<64, 128, false, false, true><<<dim3(VOCAB / 128, NROW / 64, 1), blk, 0, stream>>>(
        os_h, os_l, TDIM, fc_h, fc_l, TDIM, nullptr,
        OUT, nullptr, nullptr, VOCAB, TDIM, 0, 0, 0, 1.0f);
    softmax_vocab<<<dim3(NROW), blk, 0, stream>>>(OUT);
}